// Round 15
// baseline (240.401 us; speedup 1.0000x reference)
//
#include <hip/hip_runtime.h>

#define T_SEQ 2048
#define DM 1024
#define NH 16
#define DKH 64
#define NB 2
#define M_ROWS (NB * T_SEQ)  // 4096
#define QSCALE 0.18033688011112042f  // 0.125 * log2(e): exp2 domain

using bf16x8 = __attribute__((ext_vector_type(8))) __bf16;
using f32x4  = __attribute__((ext_vector_type(4))) float;
using halfx4 = __attribute__((ext_vector_type(4))) __fp16;
using halfx8 = __attribute__((ext_vector_type(8))) __fp16;
using halfx2 = __attribute__((ext_vector_type(2))) __fp16;
using uintx4 = __attribute__((ext_vector_type(4))) unsigned;

__device__ __forceinline__ short f2bf(float f) {
  unsigned u = __builtin_bit_cast(unsigned, f);
  u += 0x7fffu + ((u >> 16) & 1u);
  return (short)(u >> 16);
}

#if defined(__has_builtin) && __has_builtin(__builtin_amdgcn_cvt_pk_bf16_f32)
using bf16x2 = __attribute__((ext_vector_type(2))) __bf16;
__device__ __forceinline__ short2 pk2(float a, float b) {
  bf16x2 r = __builtin_amdgcn_cvt_pk_bf16_f32(a, b);
  return __builtin_bit_cast(short2, r);
}
#else
__device__ __forceinline__ short2 pk2(float a, float b) {
  short2 r; r.x = f2bf(a); r.y = f2bf(b); return r;
}
#endif

__device__ __forceinline__ short2 pkh(float a, float b) {  // f32x2 -> f16x2 (RTZ)
  halfx2 r = __builtin_amdgcn_cvt_pkrtz(a, b);
  return __builtin_bit_cast(short2, r);
}

#if defined(__has_builtin) && __has_builtin(__builtin_amdgcn_exp2f)
__device__ __forceinline__ float fexp2(float x) { return __builtin_amdgcn_exp2f(x); }
#else
__device__ __forceinline__ float fexp2(float x) { return exp2f(x); }
#endif

// gfx950 cross-lane row swaps (for P-fragment redistribution in PV).
#if defined(__has_builtin) && __has_builtin(__builtin_amdgcn_permlane32_swap) && \
    __has_builtin(__builtin_amdgcn_permlane16_swap)
using uintx2 = __attribute__((ext_vector_type(2))) unsigned;
__device__ __forceinline__ void swap32(unsigned& a, unsigned& b) {
  uintx2 r = __builtin_amdgcn_permlane32_swap(a, b, false, false);
  a = r.x; b = r.y;
}
__device__ __forceinline__ void swap16(unsigned& a, unsigned& b) {
  uintx2 r = __builtin_amdgcn_permlane16_swap(a, b, false, false);
  a = r.x; b = r.y;
}
#else
__device__ __forceinline__ void swap32(unsigned& a, unsigned& b) {
  asm volatile("v_permlane32_swap_b32 %0, %1" : "+v"(a), "+v"(b));
}
__device__ __forceinline__ void swap16(unsigned& a, unsigned& b) {
  asm volatile("v_permlane16_swap_b32 %0, %1" : "+v"(a), "+v"(b));
}
#endif

#define GLD16(g, l)                                                            \
  __builtin_amdgcn_global_load_lds(                                            \
      (const __attribute__((address_space(1))) void*)(g),                      \
      (__attribute__((address_space(3))) void*)(l), 16, 0, 0)

// ---------- prep_all: z<3 = x fp32->bf16 (+mask in z0); z in 3..6 = W^T ------
// (R13 verbatim, correctness-proven.)
__global__ __launch_bounds__(256) void prep_all(
    const float* __restrict__ q, const float* __restrict__ k,
    const float* __restrict__ v, const int* __restrict__ mask,
    const float* __restrict__ w0, const float* __restrict__ w1,
    const float* __restrict__ w2, const float* __restrict__ w3,
    short* __restrict__ dst, short* __restrict__ wdst,
    float* __restrict__ mf) {
  const int z = blockIdx.z;
  if (z < 3) {
    const float* s = z == 0 ? q : (z == 1 ? k : v);
    short* d = dst + (size_t)z * (M_ROWS * DM);
    const int bid = blockIdx.y * 16 + blockIdx.x;  // 256 blocks
    const int n4 = M_ROWS * DM / 4;
    for (int i = bid * 256 + threadIdx.x; i < n4; i += 256 * 256) {
      float4 f = *(const float4*)(s + i * 4);
      short2 a = pk2(f.x, f.y), b = pk2(f.z, f.w);
      short4 o = {a.x, a.y, b.x, b.y};
      *(short4*)(d + i * 4) = o;
    }
    if (z == 0 && bid < 4) {
      int i = (bid * 256 + threadIdx.x) * 4;
      int4 m = *(const int4*)(mask + i);
      float4 o = {m.x ? 0.f : -1e38f, m.y ? 0.f : -1e38f,
                  m.z ? 0.f : -1e38f, m.w ? 0.f : -1e38f};
      *(float4*)(mf + i) = o;
    }
    return;
  }
  // W transpose: [k][n] fp32 -> [n][k] bf16
  __shared__ short T[64][72];
  const int wz = z - 3;
  const float* W = wz == 0 ? w0 : wz == 1 ? w1 : wz == 2 ? w2 : w3;
  short* D = wdst + (size_t)wz * (DM * DM);
  const int k0 = blockIdx.x * 64, n0 = blockIdx.y * 64;
  const int r = threadIdx.x >> 2, cs = (threadIdx.x & 3) * 16;
#pragma unroll
  for (int j = 0; j < 4; ++j) {
    float4 f = *(const float4*)(W + (size_t)(k0 + r) * DM + n0 + cs + j * 4);
    short2 a = pk2(f.x, f.y), b = pk2(f.z, f.w);
    short4 o = {a.x, a.y, b.x, b.y};
    *(short4*)&T[r][cs + j * 4] = o;
  }
  __syncthreads();
  short tmp[16];
#pragma unroll
  for (int i = 0; i < 16; ++i) tmp[i] = T[cs + i][r];
  *(int4*)(D + (size_t)(n0 + r) * DM + k0 + cs) = *(const int4*)&tmp[0];
  *(int4*)(D + (size_t)(n0 + r) * DM + k0 + cs + 8) = *(const int4*)&tmp[8];
}

// ---------- QKV GEMM (2-buffer form — measured optimum 56.0 us; R14 3-ring
// reverted: sync-structure ladder measured 2-buf 56.0 < 3-ring 58.1 < 4-ring 59.0)
// z<2: headsplit bf16 [b][h][t][dk] scalar coalesced (z==0 folds QSCALE);
// z==2: V^T [b][h][dk][t] in F16 (short4 over 4 consecutive t).
__global__ __launch_bounds__(512) void gemm_qkv(
    const short* __restrict__ A_, const short* __restrict__ Bt_,
    const float* __restrict__ b0, const float* __restrict__ b1,
    const float* __restrict__ b2, short* __restrict__ Y) {
  __shared__ short As[2][4096];
  __shared__ short Bs[2][4096];
  const int z = blockIdx.z;
  const short* A = A_ + (size_t)z * (M_ROWS * DM);
  const short* Bt = Bt_ + (size_t)z * (DM * DM);
  short* Yz = Y + (size_t)z * ((size_t)M_ROWS * DM);
  const float* bias = z == 0 ? b0 : (z == 1 ? b1 : b2);
  const int m0 = blockIdx.x * 128, n0 = blockIdx.y * 128;
  const int tid = threadIdx.x, w = tid >> 6, lane = tid & 63;
  const int quad = lane >> 4, lm = lane & 15, wa = w & 1, wb = w >> 1;

  const short* Ag = A + (size_t)(m0 + w * 16 + lm) * DM + quad * 8;
  const short* Bg = Bt + (size_t)(n0 + w * 16 + lm) * DM + quad * 8;

  f32x4 acc[4][2];
#pragma unroll
  for (int i = 0; i < 4; ++i)
#pragma unroll
    for (int j = 0; j < 2; ++j) acc[i][j] = (f32x4){0.f, 0.f, 0.f, 0.f};

  GLD16(Ag, &As[0][w * 512]);
  GLD16(Bg, &Bs[0][w * 512]);

  for (int kt = 0; kt < DM / 32; ++kt) {
    const int cb = kt & 1;
    __syncthreads();
    if (kt + 1 < DM / 32) {
      GLD16(Ag + (kt + 1) * 32, &As[cb ^ 1][w * 512]);
      GLD16(Bg + (kt + 1) * 32, &Bs[cb ^ 1][w * 512]);
    }
    bf16x8 af[4], bfr[2];
#pragma unroll
    for (int i = 0; i < 4; ++i)
      af[i] = *(const bf16x8*)&As[cb][(wa * 4 + i) * 512 + quad * 128 + lm * 8];
#pragma unroll
    for (int j = 0; j < 2; ++j)
      bfr[j] = *(const bf16x8*)&Bs[cb][(wb * 2 + j) * 512 + quad * 128 + lm * 8];
#pragma unroll
    for (int mi = 0; mi < 4; ++mi)
#pragma unroll
      for (int j = 0; j < 2; ++j)
        acc[mi][j] = __builtin_amdgcn_mfma_f32_16x16x32_bf16(
            af[mi], bfr[j], acc[mi][j], 0, 0, 0);
  }

  if (z < 2) {
#pragma unroll
    for (int j = 0; j < 2; ++j) {
      const int f = n0 + (wb * 2 + j) * 16 + lm;
      const float bv = bias[f];
      const int h = f >> 6, dk = f & 63;
#pragma unroll
      for (int mi = 0; mi < 4; ++mi)
#pragma unroll
        for (int r = 0; r < 4; ++r) {
          const int m = m0 + (wa * 4 + mi) * 16 + quad * 4 + r;
          float val = acc[mi][j][r] + bv;
          if (z == 0) val *= QSCALE;
          const int b = m >> 11, tt = m & (T_SEQ - 1);
          Yz[(((size_t)(b * NH + h) << 11) + tt) * DKH + dk] = f2bf(val);
        }
    }
  } else {  // V^T [b][h][dk][t] F16
#pragma unroll
    for (int j = 0; j < 2; ++j) {
      const int f = n0 + (wb * 2 + j) * 16 + lm;
      const float bv = bias[f];
      const int h = f >> 6, dk = f & 63;
#pragma unroll
      for (int mi = 0; mi < 4; ++mi) {
        const int t = m0 + (wa * 4 + mi) * 16 + quad * 4;
        const int b = t >> 11, tt = t & (T_SEQ - 1);
        short2 a = pkh(acc[mi][j][0] + bv, acc[mi][j][1] + bv);
        short2 c = pkh(acc[mi][j][2] + bv, acc[mi][j][3] + bv);
        short4 o = {a.x, a.y, c.x, c.y};
        *(short4*)(Yz + (((size_t)(b * NH + h) * DKH + dk) << 11) + tt) = o;
      }
    }
  }
}

// ---------- out-proj GEMM: 8-wave 128x128 + T3/T4 ring (R12, proven win) -----
__global__ __launch_bounds__(512) void gemm_out(
    const short* __restrict__ A, const short* __restrict__ Bt,
    const float* __restrict__ bias, float* __restrict__ Yf) {
  __shared__ short As[4][4096];
  __shared__ short Bs[4][4096];
  const int m0 = blockIdx.x * 128, n0 = blockIdx.y * 128;
  const int tid = threadIdx.x, w = tid >> 6, lane = tid & 63;
  const int quad = lane >> 4, lm = lane & 15, wa = w & 1, wb = w >> 1;
  const int NT = DM / 32;

  const short* Ag = A + (size_t)(m0 + w * 16 + lm) * DM + quad * 8;
  const short* Bg = Bt + (size_t)(n0 + w * 16 + lm) * DM + quad * 8;

  f32x4 acc[4][2];
#pragma unroll
  for (int i = 0; i < 4; ++i)
#pragma unroll
    for (int j = 0; j < 2; ++j) acc[i][j] = (f32x4){0.f, 0.f, 0.f, 0.f};

  GLD16(Ag, &As[0][w * 512]);
  GLD16(Bg, &Bs[0][w * 512]);
  GLD16(Ag + 32, &As[1][w * 512]);
  GLD16(Bg + 32, &Bs[1][w * 512]);

  for (int kt = 0; kt < NT; ++kt) {
    const int cb = kt & 3;
    if (kt + 2 < NT) {
      GLD16(Ag + (kt + 2) * 32, &As[(kt + 2) & 3][w * 512]);
      GLD16(Bg + (kt + 2) * 32, &Bs[(kt + 2) & 3][w * 512]);
    }
    if (kt + 2 < NT)      asm volatile("s_waitcnt vmcnt(4)" ::: "memory");
    else if (kt + 1 < NT) asm volatile("s_waitcnt vmcnt(2)" ::: "memory");
    else                  asm volatile("s_waitcnt vmcnt(0)" ::: "memory");
    __builtin_amdgcn_s_barrier();
    __builtin_amdgcn_sched_barrier(0);

    bf16x8 af[4], bfr[2];
#pragma unroll
    for (int i = 0; i < 4; ++i)
      af[i] = *(const bf16x8*)&As[cb][(wa * 4 + i) * 512 + quad * 128 + lm * 8];
#pragma unroll
    for (int j = 0; j < 2; ++j)
      bfr[j] = *(const bf16x8*)&Bs[cb][(wb * 2 + j) * 512 + quad * 128 + lm * 8];
#pragma unroll
    for (int mi = 0; mi < 4; ++mi)
#pragma unroll
      for (int j = 0; j < 2; ++j)
        acc[mi][j] = __builtin_amdgcn_mfma_f32_16x16x32_bf16(
            af[mi], bfr[j], acc[mi][j], 0, 0, 0);
  }

#pragma unroll
  for (int j = 0; j < 2; ++j) {
    const int n = n0 + (wb * 2 + j) * 16 + lm;
    const float bv = bias[n];
#pragma unroll
    for (int mi = 0; mi < 4; ++mi)
#pragma unroll
      for (int r = 0; r < 4; ++r) {
        const int m = m0 + (wa * 4 + mi) * 16 + quad * 4 + r;
        Yf[(size_t)m * DM + n] = acc[mi][j][r] + bv;
      }
  }
}

// ---------- flash attention: 512 thr, 32 q/wave, 128-key tiles ---------------
// (R11 verbatim — T3/T4 ring, proven: attn ~54-58 us, refcheck passed.)
__global__ __launch_bounds__(512) void attn_kernel(
    const short* __restrict__ Qh, const short* __restrict__ Kh,
    const short* __restrict__ Vt, const float* __restrict__ mf,
    short* __restrict__ Ao) {
  __shared__ short Ks[4][8192];
  __shared__ short Vs[4][8192];
  __shared__ float Ms[T_SEQ];
  const int id = blockIdx.x + gridDim.x * blockIdx.y;
  const int bh = id & 31, qt = id >> 5;  // qt in [0,8)
  const int b = bh >> 4, h = bh & (NH - 1);
  const int tid = threadIdx.x, w = tid >> 6, lane = tid & 63;
  const int quad = lane >> 4, lm = lane & 15;
  const size_t base = (size_t)bh * T_SEQ * DKH;
  const float* mp = mf + b * T_SEQ;
  const int q0 = qt * 256 + w * 32;  // frag A rows q0+lm, frag B rows q0+16+lm

  const short* qpA = Qh + base + (size_t)(q0 + lm) * DKH;
  const short* qpB = qpA + (size_t)16 * DKH;
  const bf16x8 qbA0 = *(const bf16x8*)(qpA + quad * 8);
  const bf16x8 qbA1 = *(const bf16x8*)(qpA + 32 + quad * 8);
  const bf16x8 qbB0 = *(const bf16x8*)(qpB + quad * 8);
  const bf16x8 qbB1 = *(const bf16x8*)(qpB + 32 + quad * 8);

  const int sw = w & 3;
  const bool isV = w >= 4;
  const short* Kg = Kh + base + (size_t)(sw * 16 + lm) * DKH + quad * 8;
  const short* Vg = Vt + base + (size_t)(sw * 16 + lm) * T_SEQ + quad * 8;

  // mask -> LDS once: wave w covers floats [w*256, (w+1)*256)
  GLD16(mp + w * 256 + lane * 4, &Ms[w * 256]);

  f32x4 otA[4], otB[4];
#pragma unroll
  for (int i = 0; i < 4; ++i) {
    otA[i] = (f32x4){0.f, 0.f, 0.f, 0.f};
    otB[i] = (f32x4){0.f, 0.f, 0.f, 0.f};
  }
  float lA = 0.f, lB = 0.f;

  auto stageK = [&](int buf, int key) {
    GLD16(Kg + (size_t)key * DKH, &Ks[buf][sw * 1024]);
    GLD16(Kg + (size_t)key * DKH + 32, &Ks[buf][sw * 1024 + 512]);
    GLD16(Kg + (size_t)(key + 64) * DKH, &Ks[buf][(sw + 4) * 1024]);
    GLD16(Kg + (size_t)(key + 64) * DKH + 32, &Ks[buf][(sw + 4) * 1024 + 512]);
  };
  auto stageV = [&](int buf, int key) {
    GLD16(Vg + key, &Vs[buf][sw * 2048]);
    GLD16(Vg + key + 32, &Vs[buf][sw * 2048 + 512]);
    GLD16(Vg + key + 64, &Vs[buf][sw * 2048 + 1024]);
    GLD16(Vg + key + 96, &Vs[buf][sw * 2048 + 1536]);
  };

  // prologue: tiles 0 and 1 in flight (8 GLD16/wave + 1 mask)
  if (!isV) { stageK(0, 0); stageK(1, 128); }
  else      { stageV(0, 0); stageV(1, 128); }

  for (int kt = 0; kt < T_SEQ / 128; ++kt) {
    const int cb = kt & 3;
    const int key0 = kt * 128;
    if (kt + 2 < T_SEQ / 128) {
      if (!isV) stageK((kt + 2) & 3, key0 + 256);
      else      stageV((kt + 2) & 3, key0 + 256);
    }
    // counted wait: own tile-kt loads complete; 2 tiles stay in flight.
    if (kt + 2 < T_SEQ / 128)      asm volatile("s_waitcnt vmcnt(8)" ::: "memory");
    else if (kt + 1 < T_SEQ / 128) asm volatile("s_waitcnt vmcnt(4)" ::: "memory");
    else                           asm volatile("s_waitcnt vmcnt(0)" ::: "memory");
    __builtin_amdgcn_s_barrier();
    __builtin_amdgcn_sched_barrier(0);

    // S^T per 16-key subtile; each ka read feeds both q-fragments.
    halfx8 pbA[4], pbB[4];
#pragma unroll
    for (int kp = 0; kp < 4; ++kp) {
      unsigned peA0, peA1, poA0, poA1;
      unsigned peB0, peB1, poB0, poB1;
#pragma unroll
      for (int hf = 0; hf < 2; ++hf) {
        const int nt = kp * 2 + hf;
        bf16x8 ka0 = *(const bf16x8*)&Ks[cb][nt * 1024 + quad * 128 + lm * 8];
        bf16x8 ka1 = *(const bf16x8*)&Ks[cb][nt * 1024 + 512 + quad * 128 + lm * 8];
        f32x4 sA = (f32x4){0.f, 0.f, 0.f, 0.f};
        sA = __builtin_amdgcn_mfma_f32_16x16x32_bf16(ka0, qbA0, sA, 0, 0, 0);
        sA = __builtin_amdgcn_mfma_f32_16x16x32_bf16(ka1, qbA1, sA, 0, 0, 0);
        f32x4 sB = (f32x4){0.f, 0.f, 0.f, 0.f};
        sB = __builtin_amdgcn_mfma_f32_16x16x32_bf16(ka0, qbB0, sB, 0, 0, 0);
        sB = __builtin_amdgcn_mfma_f32_16x16x32_bf16(ka1, qbB1, sB, 0, 0, 0);
        const float4 m4 = *(const float4*)&Ms[key0 + nt * 16 + quad * 4];
        float a0 = fexp2(sA[0] + m4.x);
        float a1 = fexp2(sA[1] + m4.y);
        float a2 = fexp2(sA[2] + m4.z);
        float a3 = fexp2(sA[3] + m4.w);
        lA += (a0 + a1) + (a2 + a3);
        float b0 = fexp2(sB[0] + m4.x);
        float b1 = fexp2(sB[1] + m4.y);
        float b2 = fexp2(sB[2] + m4.z);
        float b3 = fexp2(sB[3] + m4.w);
        lB += (b0 + b1) + (b2 + b3);
        unsigned loA = __builtin_bit_cast(unsigned, pkh(a0, a1));
        unsigned hiA = __builtin_bit_cast(unsigned, pkh(a2, a3));
        unsigned loB = __builtin_bit_cast(unsigned, pkh(b0, b1));
        unsigned hiB = __builtin_bit_cast(unsigned, pkh(b2, b3));
        if (hf == 0) {
          peA0 = loA; peA1 = hiA; peB0 = loB; peB1 = hiB;
        } else {
          poA0 = loA; poA1 = hiA; poB0 = loB; poB1 = hiB;
        }
      }
      {
        unsigned x0 = peA0, y0 = poA0, x1 = peA1, y1 = poA1;
        swap32(x0, y0); swap16(x0, y0);
        swap32(x1, y1); swap16(x1, y1);
        pbA[kp] = __builtin_bit_cast(halfx8, (uintx4){x0, x1, y0, y1});
      }
      {
        unsigned x0 = peB0, y0 = poB0, x1 = peB1, y1 = poB1;
        swap32(x0, y0); swap16(x0, y0);
        swap32(x1, y1); swap16(x1, y1);
        pbB[kp] = __builtin_bit_cast(halfx8, (uintx4){x0, x1, y0, y1});
      }
    }

    // O^T += V^T.P^T : each va read feeds both fragments' MFMAs.
#pragma unroll
    for (int nt2 = 0; nt2 < 4; ++nt2) {
#pragma unroll
      for (int kp = 0; kp < 4; ++kp) {
        halfx8 va =
            *(const halfx8*)&Vs[cb][nt2 * 2048 + kp * 512 + quad * 128 + lm * 8];
        otA[nt2] =
            __builtin_amdgcn_mfma_f32_16x16x32_f16(va, pbA[kp], otA[nt2], 0, 0, 0);
        otB[nt2] =
            __builtin_amdgcn_mfma_f32_16x16x32_f16(va, pbB[kp], otB[nt2], 0, 0, 0);
      }
    }
  }
  lA += __shfl_xor(lA, 16, 64);
  lA += __shfl_xor(lA, 32, 64);
  lB += __shfl_xor(lB, 16, 64);
  lB += __shfl_xor(lB, 32, 64);
  const float invA = 1.f / lA;
  const float invB = 1.f / lB;
  const size_t rowA = (size_t)(b * T_SEQ + q0 + lm) * DM + h * DKH;
  const size_t rowB = rowA + (size_t)16 * DM;
#pragma unroll
  for (int nt = 0; nt < 4; ++nt) {
    short2 a = pk2(otA[nt][0] * invA, otA[nt][1] * invA);
    short2 c = pk2(otA[nt][2] * invA, otA[nt][3] * invA);
    short4 o4 = {a.x, a.y, c.x, c.y};
    *(short4*)(Ao + rowA + nt * 16 + quad * 4) = o4;
    short2 e = pk2(otB[nt][0] * invB, otB[nt][1] * invB);
    short2 g = pk2(otB[nt][2] * invB, otB[nt][3] * invB);
    short4 o5 = {e.x, e.y, g.x, g.y};
    *(short4*)(Ao + rowB + nt * 16 + quad * 4) = o5;
  }
}

extern "C" void kernel_launch(void* const* d_in, const int* in_sizes, int n_in,
                              void* d_out, int out_size, void* d_ws, size_t ws_size,
                              hipStream_t stream) {
  const float* q = (const float*)d_in[0];
  const float* k = (const float*)d_in[1];
  const float* v = (const float*)d_in[2];
  const int* mk = (const int*)d_in[3];
  const float* Wq = (const float*)d_in[4];
  const float* bq = (const float*)d_in[5];
  const float* Wk = (const float*)d_in[6];
  const float* bk = (const float*)d_in[7];
  const float* Wv = (const float*)d_in[8];
  const float* bv = (const float*)d_in[9];
  const float* Wo = (const float*)d_in[10];
  const float* bo = (const float*)d_in[11];

  const size_t XE = (size_t)M_ROWS * DM;  // 4194304
  const size_t WE = (size_t)DM * DM;      // 1048576
  short* xb = (short*)d_ws;               // 3*XE (dead after QKV gemm)
  short* Wt = xb + 3 * XE;                // 4*WE
  short* Qh = Wt + 4 * WE;                // 3*XE: Qh, Kh, Vt(f16)
  float* mf = (float*)(Qh + 3 * XE);      // 4096 floats
  short* Ao = xb;                         // alias

  prep_all<<<dim3(16, 16, 7), 256, 0, stream>>>(q, k, v, mk, Wq, Wk, Wv, Wo,
                                                xb, Wt, mf);
  gemm_qkv<<<dim3(M_ROWS / 128, DM / 128, 3), 512, 0, stream>>>(
      xb, Wt, bq, bk, bv, Qh);
  attn_kernel<<<dim3(T_SEQ / 256, NB * NH), 512, 0, stream>>>(
      Qh, Qh + XE, Qh + 2 * XE, mf, Ao);
  gemm_out<<<dim3(M_ROWS / 128, DM / 128), 512, 0, stream>>>(
      Ao, Wt + 3 * WE, bo, (float*)d_out);
}

// Round 16
// 235.575 us; speedup vs baseline: 1.0205x; 1.0205x over previous
//
#include <hip/hip_runtime.h>

#define T_SEQ 2048
#define DM 1024
#define NH 16
#define DKH 64
#define NB 2
#define M_ROWS (NB * T_SEQ)  // 4096
#define QSCALE 0.18033688011112042f  // 0.125 * log2(e): exp2 domain

using bf16x8 = __attribute__((ext_vector_type(8))) __bf16;
using f32x4  = __attribute__((ext_vector_type(4))) float;
using halfx4 = __attribute__((ext_vector_type(4))) __fp16;
using halfx8 = __attribute__((ext_vector_type(8))) __fp16;
using halfx2 = __attribute__((ext_vector_type(2))) __fp16;
using uintx4 = __attribute__((ext_vector_type(4))) unsigned;

__device__ __forceinline__ short f2bf(float f) {
  unsigned u = __builtin_bit_cast(unsigned, f);
  u += 0x7fffu + ((u >> 16) & 1u);
  return (short)(u >> 16);
}

#if defined(__has_builtin) && __has_builtin(__builtin_amdgcn_cvt_pk_bf16_f32)
using bf16x2 = __attribute__((ext_vector_type(2))) __bf16;
__device__ __forceinline__ short2 pk2(float a, float b) {
  bf16x2 r = __builtin_amdgcn_cvt_pk_bf16_f32(a, b);
  return __builtin_bit_cast(short2, r);
}
#else
__device__ __forceinline__ short2 pk2(float a, float b) {
  short2 r; r.x = f2bf(a); r.y = f2bf(b); return r;
}
#endif

__device__ __forceinline__ short2 pkh(float a, float b) {  // f32x2 -> f16x2 (RTZ)
  halfx2 r = __builtin_amdgcn_cvt_pkrtz(a, b);
  return __builtin_bit_cast(short2, r);
}

#if defined(__has_builtin) && __has_builtin(__builtin_amdgcn_exp2f)
__device__ __forceinline__ float fexp2(float x) { return __builtin_amdgcn_exp2f(x); }
#else
__device__ __forceinline__ float fexp2(float x) { return exp2f(x); }
#endif

// gfx950 cross-lane row swaps (for P-fragment redistribution in PV).
#if defined(__has_builtin) && __has_builtin(__builtin_amdgcn_permlane32_swap) && \
    __has_builtin(__builtin_amdgcn_permlane16_swap)
using uintx2 = __attribute__((ext_vector_type(2))) unsigned;
__device__ __forceinline__ void swap32(unsigned& a, unsigned& b) {
  uintx2 r = __builtin_amdgcn_permlane32_swap(a, b, false, false);
  a = r.x; b = r.y;
}
__device__ __forceinline__ void swap16(unsigned& a, unsigned& b) {
  uintx2 r = __builtin_amdgcn_permlane16_swap(a, b, false, false);
  a = r.x; b = r.y;
}
#else
__device__ __forceinline__ void swap32(unsigned& a, unsigned& b) {
  asm volatile("v_permlane32_swap_b32 %0, %1" : "+v"(a), "+v"(b));
}
__device__ __forceinline__ void swap16(unsigned& a, unsigned& b) {
  asm volatile("v_permlane16_swap_b32 %0, %1" : "+v"(a), "+v"(b));
}
#endif

#define GLD16(g, l)                                                            \
  __builtin_amdgcn_global_load_lds(                                            \
      (const __attribute__((address_space(1))) void*)(g),                      \
      (__attribute__((address_space(3))) void*)(l), 16, 0, 0)

// ---------- prep_all: z<3 = x fp32->bf16 (+mask in z0); z in 3..6 = W^T ------
// (R13 verbatim, correctness-proven.)
__global__ __launch_bounds__(256) void prep_all(
    const float* __restrict__ q, const float* __restrict__ k,
    const float* __restrict__ v, const int* __restrict__ mask,
    const float* __restrict__ w0, const float* __restrict__ w1,
    const float* __restrict__ w2, const float* __restrict__ w3,
    short* __restrict__ dst, short* __restrict__ wdst,
    float* __restrict__ mf) {
  const int z = blockIdx.z;
  if (z < 3) {
    const float* s = z == 0 ? q : (z == 1 ? k : v);
    short* d = dst + (size_t)z * (M_ROWS * DM);
    const int bid = blockIdx.y * 16 + blockIdx.x;  // 256 blocks
    const int n4 = M_ROWS * DM / 4;
    for (int i = bid * 256 + threadIdx.x; i < n4; i += 256 * 256) {
      float4 f = *(const float4*)(s + i * 4);
      short2 a = pk2(f.x, f.y), b = pk2(f.z, f.w);
      short4 o = {a.x, a.y, b.x, b.y};
      *(short4*)(d + i * 4) = o;
    }
    if (z == 0 && bid < 4) {
      int i = (bid * 256 + threadIdx.x) * 4;
      int4 m = *(const int4*)(mask + i);
      float4 o = {m.x ? 0.f : -1e38f, m.y ? 0.f : -1e38f,
                  m.z ? 0.f : -1e38f, m.w ? 0.f : -1e38f};
      *(float4*)(mf + i) = o;
    }
    return;
  }
  // W transpose: [k][n] fp32 -> [n][k] bf16
  __shared__ short T[64][72];
  const int wz = z - 3;
  const float* W = wz == 0 ? w0 : wz == 1 ? w1 : wz == 2 ? w2 : w3;
  short* D = wdst + (size_t)wz * (DM * DM);
  const int k0 = blockIdx.x * 64, n0 = blockIdx.y * 64;
  const int r = threadIdx.x >> 2, cs = (threadIdx.x & 3) * 16;
#pragma unroll
  for (int j = 0; j < 4; ++j) {
    float4 f = *(const float4*)(W + (size_t)(k0 + r) * DM + n0 + cs + j * 4);
    short2 a = pk2(f.x, f.y), b = pk2(f.z, f.w);
    short4 o = {a.x, a.y, b.x, b.y};
    *(short4*)&T[r][cs + j * 4] = o;
  }
  __syncthreads();
  short tmp[16];
#pragma unroll
  for (int i = 0; i < 16; ++i) tmp[i] = T[cs + i][r];
  *(int4*)(D + (size_t)(n0 + r) * DM + k0 + cs) = *(const int4*)&tmp[0];
  *(int4*)(D + (size_t)(n0 + r) * DM + k0 + cs + 8) = *(const int4*)&tmp[8];
}

// ---------- QKV GEMM (2-buffer form — measured optimum 56.0 us) --------------
// z<2: headsplit bf16 [b][h][t][dk] scalar coalesced (z==0 folds QSCALE);
// z==2: V^T [b][h][dk][t] in F16 (short4 over 4 consecutive t).
__global__ __launch_bounds__(512) void gemm_qkv(
    const short* __restrict__ A_, const short* __restrict__ Bt_,
    const float* __restrict__ b0, const float* __restrict__ b1,
    const float* __restrict__ b2, short* __restrict__ Y) {
  __shared__ short As[2][4096];
  __shared__ short Bs[2][4096];
  const int z = blockIdx.z;
  const short* A = A_ + (size_t)z * (M_ROWS * DM);
  const short* Bt = Bt_ + (size_t)z * (DM * DM);
  short* Yz = Y + (size_t)z * ((size_t)M_ROWS * DM);
  const float* bias = z == 0 ? b0 : (z == 1 ? b1 : b2);
  const int m0 = blockIdx.x * 128, n0 = blockIdx.y * 128;
  const int tid = threadIdx.x, w = tid >> 6, lane = tid & 63;
  const int quad = lane >> 4, lm = lane & 15, wa = w & 1, wb = w >> 1;

  const short* Ag = A + (size_t)(m0 + w * 16 + lm) * DM + quad * 8;
  const short* Bg = Bt + (size_t)(n0 + w * 16 + lm) * DM + quad * 8;

  f32x4 acc[4][2];
#pragma unroll
  for (int i = 0; i < 4; ++i)
#pragma unroll
    for (int j = 0; j < 2; ++j) acc[i][j] = (f32x4){0.f, 0.f, 0.f, 0.f};

  GLD16(Ag, &As[0][w * 512]);
  GLD16(Bg, &Bs[0][w * 512]);

  for (int kt = 0; kt < DM / 32; ++kt) {
    const int cb = kt & 1;
    __syncthreads();
    if (kt + 1 < DM / 32) {
      GLD16(Ag + (kt + 1) * 32, &As[cb ^ 1][w * 512]);
      GLD16(Bg + (kt + 1) * 32, &Bs[cb ^ 1][w * 512]);
    }
    bf16x8 af[4], bfr[2];
#pragma unroll
    for (int i = 0; i < 4; ++i)
      af[i] = *(const bf16x8*)&As[cb][(wa * 4 + i) * 512 + quad * 128 + lm * 8];
#pragma unroll
    for (int j = 0; j < 2; ++j)
      bfr[j] = *(const bf16x8*)&Bs[cb][(wb * 2 + j) * 512 + quad * 128 + lm * 8];
#pragma unroll
    for (int mi = 0; mi < 4; ++mi)
#pragma unroll
      for (int j = 0; j < 2; ++j)
        acc[mi][j] = __builtin_amdgcn_mfma_f32_16x16x32_bf16(
            af[mi], bfr[j], acc[mi][j], 0, 0, 0);
  }

  if (z < 2) {
#pragma unroll
    for (int j = 0; j < 2; ++j) {
      const int f = n0 + (wb * 2 + j) * 16 + lm;
      const float bv = bias[f];
      const int h = f >> 6, dk = f & 63;
#pragma unroll
      for (int mi = 0; mi < 4; ++mi)
#pragma unroll
        for (int r = 0; r < 4; ++r) {
          const int m = m0 + (wa * 4 + mi) * 16 + quad * 4 + r;
          float val = acc[mi][j][r] + bv;
          if (z == 0) val *= QSCALE;
          const int b = m >> 11, tt = m & (T_SEQ - 1);
          Yz[(((size_t)(b * NH + h) << 11) + tt) * DKH + dk] = f2bf(val);
        }
    }
  } else {  // V^T [b][h][dk][t] F16
#pragma unroll
    for (int j = 0; j < 2; ++j) {
      const int f = n0 + (wb * 2 + j) * 16 + lm;
      const float bv = bias[f];
      const int h = f >> 6, dk = f & 63;
#pragma unroll
      for (int mi = 0; mi < 4; ++mi) {
        const int t = m0 + (wa * 4 + mi) * 16 + quad * 4;
        const int b = t >> 11, tt = t & (T_SEQ - 1);
        short2 a = pkh(acc[mi][j][0] + bv, acc[mi][j][1] + bv);
        short2 c = pkh(acc[mi][j][2] + bv, acc[mi][j][3] + bv);
        short4 o = {a.x, a.y, c.x, c.y};
        *(short4*)(Yz + (((size_t)(b * NH + h) * DKH + dk) << 11) + tt) = o;
      }
    }
  }
}

// ---------- out-proj GEMM: 8-wave 128x128 + T3/T4 ring (R12, proven win) -----
__global__ __launch_bounds__(512) void gemm_out(
    const short* __restrict__ A, const short* __restrict__ Bt,
    const float* __restrict__ bias, float* __restrict__ Yf) {
  __shared__ short As[4][4096];
  __shared__ short Bs[4][4096];
  const int m0 = blockIdx.x * 128, n0 = blockIdx.y * 128;
  const int tid = threadIdx.x, w = tid >> 6, lane = tid & 63;
  const int quad = lane >> 4, lm = lane & 15, wa = w & 1, wb = w >> 1;
  const int NT = DM / 32;

  const short* Ag = A + (size_t)(m0 + w * 16 + lm) * DM + quad * 8;
  const short* Bg = Bt + (size_t)(n0 + w * 16 + lm) * DM + quad * 8;

  f32x4 acc[4][2];
#pragma unroll
  for (int i = 0; i < 4; ++i)
#pragma unroll
    for (int j = 0; j < 2; ++j) acc[i][j] = (f32x4){0.f, 0.f, 0.f, 0.f};

  GLD16(Ag, &As[0][w * 512]);
  GLD16(Bg, &Bs[0][w * 512]);
  GLD16(Ag + 32, &As[1][w * 512]);
  GLD16(Bg + 32, &Bs[1][w * 512]);

  for (int kt = 0; kt < NT; ++kt) {
    const int cb = kt & 3;
    if (kt + 2 < NT) {
      GLD16(Ag + (kt + 2) * 32, &As[(kt + 2) & 3][w * 512]);
      GLD16(Bg + (kt + 2) * 32, &Bs[(kt + 2) & 3][w * 512]);
    }
    if (kt + 2 < NT)      asm volatile("s_waitcnt vmcnt(4)" ::: "memory");
    else if (kt + 1 < NT) asm volatile("s_waitcnt vmcnt(2)" ::: "memory");
    else                  asm volatile("s_waitcnt vmcnt(0)" ::: "memory");
    __builtin_amdgcn_s_barrier();
    __builtin_amdgcn_sched_barrier(0);

    bf16x8 af[4], bfr[2];
#pragma unroll
    for (int i = 0; i < 4; ++i)
      af[i] = *(const bf16x8*)&As[cb][(wa * 4 + i) * 512 + quad * 128 + lm * 8];
#pragma unroll
    for (int j = 0; j < 2; ++j)
      bfr[j] = *(const bf16x8*)&Bs[cb][(wb * 2 + j) * 512 + quad * 128 + lm * 8];
#pragma unroll
    for (int mi = 0; mi < 4; ++mi)
#pragma unroll
      for (int j = 0; j < 2; ++j)
        acc[mi][j] = __builtin_amdgcn_mfma_f32_16x16x32_bf16(
            af[mi], bfr[j], acc[mi][j], 0, 0, 0);
  }

#pragma unroll
  for (int j = 0; j < 2; ++j) {
    const int n = n0 + (wb * 2 + j) * 16 + lm;
    const float bv = bias[n];
#pragma unroll
    for (int mi = 0; mi < 4; ++mi)
#pragma unroll
      for (int r = 0; r < 4; ++r) {
        const int m = m0 + (wa * 4 + mi) * 16 + quad * 4 + r;
        Yf[(size_t)m * DM + n] = acc[mi][j][r] + bv;
      }
  }
}

// ---------- flash attention: 512 thr, 32 q/wave, 128-key tiles ---------------
// (R11 ring + mask-seeded QK accumulator: the C-in of the first QK MFMA is
// the additive mask vector — row of C/D frag = key = quad*4+r matches m4[r].
// Removes 64 v_add_f32/tile/wave from the VALU pipe; numerically identical.)
__global__ __launch_bounds__(512) void attn_kernel(
    const short* __restrict__ Qh, const short* __restrict__ Kh,
    const short* __restrict__ Vt, const float* __restrict__ mf,
    short* __restrict__ Ao) {
  __shared__ short Ks[4][8192];
  __shared__ short Vs[4][8192];
  __shared__ float Ms[T_SEQ];
  const int id = blockIdx.x + gridDim.x * blockIdx.y;
  const int bh = id & 31, qt = id >> 5;  // qt in [0,8)
  const int b = bh >> 4, h = bh & (NH - 1);
  const int tid = threadIdx.x, w = tid >> 6, lane = tid & 63;
  const int quad = lane >> 4, lm = lane & 15;
  const size_t base = (size_t)bh * T_SEQ * DKH;
  const float* mp = mf + b * T_SEQ;
  const int q0 = qt * 256 + w * 32;  // frag A rows q0+lm, frag B rows q0+16+lm

  const short* qpA = Qh + base + (size_t)(q0 + lm) * DKH;
  const short* qpB = qpA + (size_t)16 * DKH;
  const bf16x8 qbA0 = *(const bf16x8*)(qpA + quad * 8);
  const bf16x8 qbA1 = *(const bf16x8*)(qpA + 32 + quad * 8);
  const bf16x8 qbB0 = *(const bf16x8*)(qpB + quad * 8);
  const bf16x8 qbB1 = *(const bf16x8*)(qpB + 32 + quad * 8);

  const int sw = w & 3;
  const bool isV = w >= 4;
  const short* Kg = Kh + base + (size_t)(sw * 16 + lm) * DKH + quad * 8;
  const short* Vg = Vt + base + (size_t)(sw * 16 + lm) * T_SEQ + quad * 8;

  // mask -> LDS once: wave w covers floats [w*256, (w+1)*256)
  GLD16(mp + w * 256 + lane * 4, &Ms[w * 256]);

  f32x4 otA[4], otB[4];
#pragma unroll
  for (int i = 0; i < 4; ++i) {
    otA[i] = (f32x4){0.f, 0.f, 0.f, 0.f};
    otB[i] = (f32x4){0.f, 0.f, 0.f, 0.f};
  }
  float lA = 0.f, lB = 0.f;

  auto stageK = [&](int buf, int key) {
    GLD16(Kg + (size_t)key * DKH, &Ks[buf][sw * 1024]);
    GLD16(Kg + (size_t)key * DKH + 32, &Ks[buf][sw * 1024 + 512]);
    GLD16(Kg + (size_t)(key + 64) * DKH, &Ks[buf][(sw + 4) * 1024]);
    GLD16(Kg + (size_t)(key + 64) * DKH + 32, &Ks[buf][(sw + 4) * 1024 + 512]);
  };
  auto stageV = [&](int buf, int key) {
    GLD16(Vg + key, &Vs[buf][sw * 2048]);
    GLD16(Vg + key + 32, &Vs[buf][sw * 2048 + 512]);
    GLD16(Vg + key + 64, &Vs[buf][sw * 2048 + 1024]);
    GLD16(Vg + key + 96, &Vs[buf][sw * 2048 + 1536]);
  };

  // prologue: tiles 0 and 1 in flight (8 GLD16/wave + 1 mask)
  if (!isV) { stageK(0, 0); stageK(1, 128); }
  else      { stageV(0, 0); stageV(1, 128); }

  for (int kt = 0; kt < T_SEQ / 128; ++kt) {
    const int cb = kt & 3;
    const int key0 = kt * 128;
    if (kt + 2 < T_SEQ / 128) {
      if (!isV) stageK((kt + 2) & 3, key0 + 256);
      else      stageV((kt + 2) & 3, key0 + 256);
    }
    // counted wait: own tile-kt loads complete; 2 tiles stay in flight.
    if (kt + 2 < T_SEQ / 128)      asm volatile("s_waitcnt vmcnt(8)" ::: "memory");
    else if (kt + 1 < T_SEQ / 128) asm volatile("s_waitcnt vmcnt(4)" ::: "memory");
    else                           asm volatile("s_waitcnt vmcnt(0)" ::: "memory");
    __builtin_amdgcn_s_barrier();
    __builtin_amdgcn_sched_barrier(0);

    // S^T per 16-key subtile; each ka read feeds both q-fragments.
    // QK accumulator seeded with the additive mask (C-in of first MFMA).
    halfx8 pbA[4], pbB[4];
#pragma unroll
    for (int kp = 0; kp < 4; ++kp) {
      unsigned peA0, peA1, poA0, poA1;
      unsigned peB0, peB1, poB0, poB1;
#pragma unroll
      for (int hf = 0; hf < 2; ++hf) {
        const int nt = kp * 2 + hf;
        bf16x8 ka0 = *(const bf16x8*)&Ks[cb][nt * 1024 + quad * 128 + lm * 8];
        bf16x8 ka1 = *(const bf16x8*)&Ks[cb][nt * 1024 + 512 + quad * 128 + lm * 8];
        const float4 m4 = *(const float4*)&Ms[key0 + nt * 16 + quad * 4];
        const f32x4 mseed = (f32x4){m4.x, m4.y, m4.z, m4.w};
        f32x4 sA = mseed;
        sA = __builtin_amdgcn_mfma_f32_16x16x32_bf16(ka0, qbA0, sA, 0, 0, 0);
        sA = __builtin_amdgcn_mfma_f32_16x16x32_bf16(ka1, qbA1, sA, 0, 0, 0);
        f32x4 sB = mseed;
        sB = __builtin_amdgcn_mfma_f32_16x16x32_bf16(ka0, qbB0, sB, 0, 0, 0);
        sB = __builtin_amdgcn_mfma_f32_16x16x32_bf16(ka1, qbB1, sB, 0, 0, 0);
        float a0 = fexp2(sA[0]);
        float a1 = fexp2(sA[1]);
        float a2 = fexp2(sA[2]);
        float a3 = fexp2(sA[3]);
        lA += (a0 + a1) + (a2 + a3);
        float b0 = fexp2(sB[0]);
        float b1 = fexp2(sB[1]);
        float b2 = fexp2(sB[2]);
        float b3 = fexp2(sB[3]);
        lB += (b0 + b1) + (b2 + b3);
        unsigned loA = __builtin_bit_cast(unsigned, pkh(a0, a1));
        unsigned hiA = __builtin_bit_cast(unsigned, pkh(a2, a3));
        unsigned loB = __builtin_bit_cast(unsigned, pkh(b0, b1));
        unsigned hiB = __builtin_bit_cast(unsigned, pkh(b2, b3));
        if (hf == 0) {
          peA0 = loA; peA1 = hiA; peB0 = loB; peB1 = hiB;
        } else {
          poA0 = loA; poA1 = hiA; poB0 = loB; poB1 = hiB;
        }
      }
      {
        unsigned x0 = peA0, y0 = poA0, x1 = peA1, y1 = poA1;
        swap32(x0, y0); swap16(x0, y0);
        swap32(x1, y1); swap16(x1, y1);
        pbA[kp] = __builtin_bit_cast(halfx8, (uintx4){x0, x1, y0, y1});
      }
      {
        unsigned x0 = peB0, y0 = poB0, x1 = peB1, y1 = poB1;
        swap32(x0, y0); swap16(x0, y0);
        swap32(x1, y1); swap16(x1, y1);
        pbB[kp] = __builtin_bit_cast(halfx8, (uintx4){x0, x1, y0, y1});
      }
    }

    // O^T += V^T.P^T : each va read feeds both fragments' MFMAs.
#pragma unroll
    for (int nt2 = 0; nt2 < 4; ++nt2) {
#pragma unroll
      for (int kp = 0; kp < 4; ++kp) {
        halfx8 va =
            *(const halfx8*)&Vs[cb][nt2 * 2048 + kp * 512 + quad * 128 + lm * 8];
        otA[nt2] =
            __builtin_amdgcn_mfma_f32_16x16x32_f16(va, pbA[kp], otA[nt2], 0, 0, 0);
        otB[nt2] =
            __builtin_amdgcn_mfma_f32_16x16x32_f16(va, pbB[kp], otB[nt2], 0, 0, 0);
      }
    }
  }
  lA += __shfl_xor(lA, 16, 64);
  lA += __shfl_xor(lA, 32, 64);
  lB += __shfl_xor(lB, 16, 64);
  lB += __shfl_xor(lB, 32, 64);
  const float invA = 1.f / lA;
  const float invB = 1.f / lB;
  const size_t rowA = (size_t)(b * T_SEQ + q0 + lm) * DM + h * DKH;
  const size_t rowB = rowA + (size_t)16 * DM;
#pragma unroll
  for (int nt = 0; nt < 4; ++nt) {
    short2 a = pk2(otA[nt][0] * invA, otA[nt][1] * invA);
    short2 c = pk2(otA[nt][2] * invA, otA[nt][3] * invA);
    short4 o4 = {a.x, a.y, c.x, c.y};
    *(short4*)(Ao + rowA + nt * 16 + quad * 4) = o4;
    short2 e = pk2(otB[nt][0] * invB, otB[nt][1] * invB);
    short2 g = pk2(otB[nt][2] * invB, otB[nt][3] * invB);
    short4 o5 = {e.x, e.y, g.x, g.y};
    *(short4*)(Ao + rowB + nt * 16 + quad * 4) = o5;
  }
}

extern "C" void kernel_launch(void* const* d_in, const int* in_sizes, int n_in,
                              void* d_out, int out_size, void* d_ws, size_t ws_size,
                              hipStream_t stream) {
  const float* q = (const float*)d_in[0];
  const float* k = (const float*)d_in[1];
  const float* v = (const float*)d_in[2];
  const int* mk = (const int*)d_in[3];
  const float* Wq = (const float*)d_in[4];
  const float* bq = (const float*)d_in[5];
  const float* Wk = (const float*)d_in[6];
  const float* bk = (const float*)d_in[7];
  const float* Wv = (const float*)d_in[8];
  const float* bv = (const float*)d_in[9];
  const float* Wo = (const float*)d_in[10];
  const float* bo = (const float*)d_in[11];

  const size_t XE = (size_t)M_ROWS * DM;  // 4194304
  const size_t WE = (size_t)DM * DM;      // 1048576
  short* xb = (short*)d_ws;               // 3*XE (dead after QKV gemm)
  short* Wt = xb + 3 * XE;                // 4*WE
  short* Qh = Wt + 4 * WE;                // 3*XE: Qh, Kh, Vt(f16)
  float* mf = (float*)(Qh + 3 * XE);      // 4096 floats
  short* Ao = xb;                         // alias

  prep_all<<<dim3(16, 16, 7), 256, 0, stream>>>(q, k, v, mk, Wq, Wk, Wv, Wo,
                                                xb, Wt, mf);
  gemm_qkv<<<dim3(M_ROWS / 128, DM / 128, 3), 512, 0, stream>>>(
      xb, Wt, bq, bk, bv, Qh);
  attn_kernel<<<dim3(T_SEQ / 256, NB * NH), 512, 0, stream>>>(
      Qh, Qh + XE, Qh + 2 * XE, mf, Ao);
  gemm_out<<<dim3(M_ROWS / 128, DM / 128), 512, 0, stream>>>(
      Ao, Wt + 3 * WE, bo, (float*)d_out);
}

// Round 17
// 234.117 us; speedup vs baseline: 1.0268x; 1.0062x over previous
//
#include <hip/hip_runtime.h>

#define T_SEQ 2048
#define DM 1024
#define NH 16
#define DKH 64
#define NB 2
#define M_ROWS (NB * T_SEQ)  // 4096
#define QSCALE 0.18033688011112042f  // 0.125 * log2(e): exp2 domain

using bf16x8 = __attribute__((ext_vector_type(8))) __bf16;
using f32x4  = __attribute__((ext_vector_type(4))) float;
using halfx4 = __attribute__((ext_vector_type(4))) __fp16;
using halfx8 = __attribute__((ext_vector_type(8))) __fp16;
using halfx2 = __attribute__((ext_vector_type(2))) __fp16;
using uintx4 = __attribute__((ext_vector_type(4))) unsigned;

__device__ __forceinline__ short f2bf(float f) {
  unsigned u = __builtin_bit_cast(unsigned, f);
  u += 0x7fffu + ((u >> 16) & 1u);
  return (short)(u >> 16);
}

#if defined(__has_builtin) && __has_builtin(__builtin_amdgcn_cvt_pk_bf16_f32)
using bf16x2 = __attribute__((ext_vector_type(2))) __bf16;
__device__ __forceinline__ short2 pk2(float a, float b) {
  bf16x2 r = __builtin_amdgcn_cvt_pk_bf16_f32(a, b);
  return __builtin_bit_cast(short2, r);
}
#else
__device__ __forceinline__ short2 pk2(float a, float b) {
  short2 r; r.x = f2bf(a); r.y = f2bf(b); return r;
}
#endif

__device__ __forceinline__ short2 pkh(float a, float b) {  // f32x2 -> f16x2 (RTZ)
  halfx2 r = __builtin_amdgcn_cvt_pkrtz(a, b);
  return __builtin_bit_cast(short2, r);
}

#if defined(__has_builtin) && __has_builtin(__builtin_amdgcn_exp2f)
__device__ __forceinline__ float fexp2(float x) { return __builtin_amdgcn_exp2f(x); }
#else
__device__ __forceinline__ float fexp2(float x) { return exp2f(x); }
#endif

// gfx950 cross-lane row swaps (for P-fragment redistribution in PV).
#if defined(__has_builtin) && __has_builtin(__builtin_amdgcn_permlane32_swap) && \
    __has_builtin(__builtin_amdgcn_permlane16_swap)
using uintx2 = __attribute__((ext_vector_type(2))) unsigned;
__device__ __forceinline__ void swap32(unsigned& a, unsigned& b) {
  uintx2 r = __builtin_amdgcn_permlane32_swap(a, b, false, false);
  a = r.x; b = r.y;
}
__device__ __forceinline__ void swap16(unsigned& a, unsigned& b) {
  uintx2 r = __builtin_amdgcn_permlane16_swap(a, b, false, false);
  a = r.x; b = r.y;
}
#else
__device__ __forceinline__ void swap32(unsigned& a, unsigned& b) {
  asm volatile("v_permlane32_swap_b32 %0, %1" : "+v"(a), "+v"(b));
}
__device__ __forceinline__ void swap16(unsigned& a, unsigned& b) {
  asm volatile("v_permlane16_swap_b32 %0, %1" : "+v"(a), "+v"(b));
}
#endif

#define GLD16(g, l)                                                            \
  __builtin_amdgcn_global_load_lds(                                            \
      (const __attribute__((address_space(1))) void*)(g),                      \
      (__attribute__((address_space(3))) void*)(l), 16, 0, 0)

// ---------- prep_all: z<3 = x fp32->bf16 (+mask in z0); z in 3..6 = W^T ------
// (R13 verbatim, correctness-proven.)
__global__ __launch_bounds__(256) void prep_all(
    const float* __restrict__ q, const float* __restrict__ k,
    const float* __restrict__ v, const int* __restrict__ mask,
    const float* __restrict__ w0, const float* __restrict__ w1,
    const float* __restrict__ w2, const float* __restrict__ w3,
    short* __restrict__ dst, short* __restrict__ wdst,
    float* __restrict__ mf) {
  const int z = blockIdx.z;
  if (z < 3) {
    const float* s = z == 0 ? q : (z == 1 ? k : v);
    short* d = dst + (size_t)z * (M_ROWS * DM);
    const int bid = blockIdx.y * 16 + blockIdx.x;  // 256 blocks
    const int n4 = M_ROWS * DM / 4;
    for (int i = bid * 256 + threadIdx.x; i < n4; i += 256 * 256) {
      float4 f = *(const float4*)(s + i * 4);
      short2 a = pk2(f.x, f.y), b = pk2(f.z, f.w);
      short4 o = {a.x, a.y, b.x, b.y};
      *(short4*)(d + i * 4) = o;
    }
    if (z == 0 && bid < 4) {
      int i = (bid * 256 + threadIdx.x) * 4;
      int4 m = *(const int4*)(mask + i);
      float4 o = {m.x ? 0.f : -1e38f, m.y ? 0.f : -1e38f,
                  m.z ? 0.f : -1e38f, m.w ? 0.f : -1e38f};
      *(float4*)(mf + i) = o;
    }
    return;
  }
  // W transpose: [k][n] fp32 -> [n][k] bf16
  __shared__ short T[64][72];
  const int wz = z - 3;
  const float* W = wz == 0 ? w0 : wz == 1 ? w1 : wz == 2 ? w2 : w3;
  short* D = wdst + (size_t)wz * (DM * DM);
  const int k0 = blockIdx.x * 64, n0 = blockIdx.y * 64;
  const int r = threadIdx.x >> 2, cs = (threadIdx.x & 3) * 16;
#pragma unroll
  for (int j = 0; j < 4; ++j) {
    float4 f = *(const float4*)(W + (size_t)(k0 + r) * DM + n0 + cs + j * 4);
    short2 a = pk2(f.x, f.y), b = pk2(f.z, f.w);
    short4 o = {a.x, a.y, b.x, b.y};
    *(short4*)&T[r][cs + j * 4] = o;
  }
  __syncthreads();
  short tmp[16];
#pragma unroll
  for (int i = 0; i < 16; ++i) tmp[i] = T[cs + i][r];
  *(int4*)(D + (size_t)(n0 + r) * DM + k0 + cs) = *(const int4*)&tmp[0];
  *(int4*)(D + (size_t)(n0 + r) * DM + k0 + cs + 8) = *(const int4*)&tmp[8];
}

// ---------- QKV GEMM: corrected 3-ring (48 KB, 3 blocks/CU, counted vmcnt) ---
// Iter order: vmcnt(2) [own tile-kt loads, issued 2 iters ago — nearly free]
// -> s_barrier [tile-kt data visible to ALL waves] -> issue(kt+2) [buffer
// freed by this barrier: last read at compute(kt-1)] -> compute(kt).
// Fixes R14's 3-ring ordering (vmcnt after barrier = cross-wave visibility
// hole + serialized issue/wait). vmcnt never 0 until the 2-iter tail.
// z<2: headsplit bf16 [b][h][t][dk] (z==0 folds QSCALE);
// z==2: V^T [b][h][dk][t] in F16 (short4 over 4 consecutive t).
__global__ __launch_bounds__(512) void gemm_qkv(
    const short* __restrict__ A_, const short* __restrict__ Bt_,
    const float* __restrict__ b0, const float* __restrict__ b1,
    const float* __restrict__ b2, short* __restrict__ Y) {
  __shared__ short As[3][4096];
  __shared__ short Bs[3][4096];
  const int z = blockIdx.z;
  const short* A = A_ + (size_t)z * (M_ROWS * DM);
  const short* Bt = Bt_ + (size_t)z * (DM * DM);
  short* Yz = Y + (size_t)z * ((size_t)M_ROWS * DM);
  const float* bias = z == 0 ? b0 : (z == 1 ? b1 : b2);
  const int m0 = blockIdx.x * 128, n0 = blockIdx.y * 128;
  const int tid = threadIdx.x, w = tid >> 6, lane = tid & 63;
  const int quad = lane >> 4, lm = lane & 15, wa = w & 1, wb = w >> 1;
  const int NT = DM / 32;  // 32 K-steps

  const short* Ag = A + (size_t)(m0 + w * 16 + lm) * DM + quad * 8;
  const short* Bg = Bt + (size_t)(n0 + w * 16 + lm) * DM + quad * 8;

  f32x4 acc[4][2];
#pragma unroll
  for (int i = 0; i < 4; ++i)
#pragma unroll
    for (int j = 0; j < 2; ++j) acc[i][j] = (f32x4){0.f, 0.f, 0.f, 0.f};

  // prologue: tiles 0,1 in flight (bufs 0,1)
  GLD16(Ag, &As[0][w * 512]);
  GLD16(Bg, &Bs[0][w * 512]);
  GLD16(Ag + 32, &As[1][w * 512]);
  GLD16(Bg + 32, &Bs[1][w * 512]);

  int cb = 0;
  for (int kt = 0; kt < NT; ++kt) {
    // own tile-kt loads complete BEFORE the barrier (cross-wave visibility)
    if (kt + 1 < NT) asm volatile("s_waitcnt vmcnt(2)" ::: "memory");
    else             asm volatile("s_waitcnt vmcnt(0)" ::: "memory");
    __builtin_amdgcn_s_barrier();
    if (kt + 2 < NT) {
      const int ib = cb >= 1 ? cb - 1 : 2;  // (cb+2)%3, freed by the barrier
      GLD16(Ag + (kt + 2) * 32, &As[ib][w * 512]);
      GLD16(Bg + (kt + 2) * 32, &Bs[ib][w * 512]);
    }
    __builtin_amdgcn_sched_barrier(0);

    bf16x8 af[4], bfr[2];
#pragma unroll
    for (int i = 0; i < 4; ++i)
      af[i] = *(const bf16x8*)&As[cb][(wa * 4 + i) * 512 + quad * 128 + lm * 8];
#pragma unroll
    for (int j = 0; j < 2; ++j)
      bfr[j] = *(const bf16x8*)&Bs[cb][(wb * 2 + j) * 512 + quad * 128 + lm * 8];
#pragma unroll
    for (int mi = 0; mi < 4; ++mi)
#pragma unroll
      for (int j = 0; j < 2; ++j)
        acc[mi][j] = __builtin_amdgcn_mfma_f32_16x16x32_bf16(
            af[mi], bfr[j], acc[mi][j], 0, 0, 0);
    cb = cb == 2 ? 0 : cb + 1;
  }

  if (z < 2) {
#pragma unroll
    for (int j = 0; j < 2; ++j) {
      const int f = n0 + (wb * 2 + j) * 16 + lm;
      const float bv = bias[f];
      const int h = f >> 6, dk = f & 63;
#pragma unroll
      for (int mi = 0; mi < 4; ++mi)
#pragma unroll
        for (int r = 0; r < 4; ++r) {
          const int m = m0 + (wa * 4 + mi) * 16 + quad * 4 + r;
          float val = acc[mi][j][r] + bv;
          if (z == 0) val *= QSCALE;
          const int b = m >> 11, tt = m & (T_SEQ - 1);
          Yz[(((size_t)(b * NH + h) << 11) + tt) * DKH + dk] = f2bf(val);
        }
    }
  } else {  // V^T [b][h][dk][t] F16
#pragma unroll
    for (int j = 0; j < 2; ++j) {
      const int f = n0 + (wb * 2 + j) * 16 + lm;
      const float bv = bias[f];
      const int h = f >> 6, dk = f & 63;
#pragma unroll
      for (int mi = 0; mi < 4; ++mi) {
        const int t = m0 + (wa * 4 + mi) * 16 + quad * 4;
        const int b = t >> 11, tt = t & (T_SEQ - 1);
        short2 a = pkh(acc[mi][j][0] + bv, acc[mi][j][1] + bv);
        short2 c = pkh(acc[mi][j][2] + bv, acc[mi][j][3] + bv);
        short4 o = {a.x, a.y, c.x, c.y};
        *(short4*)(Yz + (((size_t)(b * NH + h) * DKH + dk) << 11) + tt) = o;
      }
    }
  }
}

// ---------- out-proj GEMM: 8-wave 128x128 + T3/T4 ring (R12, proven win) -----
__global__ __launch_bounds__(512) void gemm_out(
    const short* __restrict__ A, const short* __restrict__ Bt,
    const float* __restrict__ bias, float* __restrict__ Yf) {
  __shared__ short As[4][4096];
  __shared__ short Bs[4][4096];
  const int m0 = blockIdx.x * 128, n0 = blockIdx.y * 128;
  const int tid = threadIdx.x, w = tid >> 6, lane = tid & 63;
  const int quad = lane >> 4, lm = lane & 15, wa = w & 1, wb = w >> 1;
  const int NT = DM / 32;

  const short* Ag = A + (size_t)(m0 + w * 16 + lm) * DM + quad * 8;
  const short* Bg = Bt + (size_t)(n0 + w * 16 + lm) * DM + quad * 8;

  f32x4 acc[4][2];
#pragma unroll
  for (int i = 0; i < 4; ++i)
#pragma unroll
    for (int j = 0; j < 2; ++j) acc[i][j] = (f32x4){0.f, 0.f, 0.f, 0.f};

  GLD16(Ag, &As[0][w * 512]);
  GLD16(Bg, &Bs[0][w * 512]);
  GLD16(Ag + 32, &As[1][w * 512]);
  GLD16(Bg + 32, &Bs[1][w * 512]);

  for (int kt = 0; kt < NT; ++kt) {
    const int cb = kt & 3;
    if (kt + 2 < NT) {
      GLD16(Ag + (kt + 2) * 32, &As[(kt + 2) & 3][w * 512]);
      GLD16(Bg + (kt + 2) * 32, &Bs[(kt + 2) & 3][w * 512]);
    }
    if (kt + 2 < NT)      asm volatile("s_waitcnt vmcnt(4)" ::: "memory");
    else if (kt + 1 < NT) asm volatile("s_waitcnt vmcnt(2)" ::: "memory");
    else                  asm volatile("s_waitcnt vmcnt(0)" ::: "memory");
    __builtin_amdgcn_s_barrier();
    __builtin_amdgcn_sched_barrier(0);

    bf16x8 af[4], bfr[2];
#pragma unroll
    for (int i = 0; i < 4; ++i)
      af[i] = *(const bf16x8*)&As[cb][(wa * 4 + i) * 512 + quad * 128 + lm * 8];
#pragma unroll
    for (int j = 0; j < 2; ++j)
      bfr[j] = *(const bf16x8*)&Bs[cb][(wb * 2 + j) * 512 + quad * 128 + lm * 8];
#pragma unroll
    for (int mi = 0; mi < 4; ++mi)
#pragma unroll
      for (int j = 0; j < 2; ++j)
        acc[mi][j] = __builtin_amdgcn_mfma_f32_16x16x32_bf16(
            af[mi], bfr[j], acc[mi][j], 0, 0, 0);
  }

#pragma unroll
  for (int j = 0; j < 2; ++j) {
    const int n = n0 + (wb * 2 + j) * 16 + lm;
    const float bv = bias[n];
#pragma unroll
    for (int mi = 0; mi < 4; ++mi)
#pragma unroll
      for (int r = 0; r < 4; ++r) {
        const int m = m0 + (wa * 4 + mi) * 16 + quad * 4 + r;
        Yf[(size_t)m * DM + n] = acc[mi][j][r] + bv;
      }
  }
}

// ---------- flash attention: 512 thr, 32 q/wave, 128-key tiles ---------------
// (R16 verbatim — T3/T4 ring + mask-seeded QK accumulator, proven.)
__global__ __launch_bounds__(512) void attn_kernel(
    const short* __restrict__ Qh, const short* __restrict__ Kh,
    const short* __restrict__ Vt, const float* __restrict__ mf,
    short* __restrict__ Ao) {
  __shared__ short Ks[4][8192];
  __shared__ short Vs[4][8192];
  __shared__ float Ms[T_SEQ];
  const int id = blockIdx.x + gridDim.x * blockIdx.y;
  const int bh = id & 31, qt = id >> 5;  // qt in [0,8)
  const int b = bh >> 4, h = bh & (NH - 1);
  const int tid = threadIdx.x, w = tid >> 6, lane = tid & 63;
  const int quad = lane >> 4, lm = lane & 15;
  const size_t base = (size_t)bh * T_SEQ * DKH;
  const float* mp = mf + b * T_SEQ;
  const int q0 = qt * 256 + w * 32;  // frag A rows q0+lm, frag B rows q0+16+lm

  const short* qpA = Qh + base + (size_t)(q0 + lm) * DKH;
  const short* qpB = qpA + (size_t)16 * DKH;
  const bf16x8 qbA0 = *(const bf16x8*)(qpA + quad * 8);
  const bf16x8 qbA1 = *(const bf16x8*)(qpA + 32 + quad * 8);
  const bf16x8 qbB0 = *(const bf16x8*)(qpB + quad * 8);
  const bf16x8 qbB1 = *(const bf16x8*)(qpB + 32 + quad * 8);

  const int sw = w & 3;
  const bool isV = w >= 4;
  const short* Kg = Kh + base + (size_t)(sw * 16 + lm) * DKH + quad * 8;
  const short* Vg = Vt + base + (size_t)(sw * 16 + lm) * T_SEQ + quad * 8;

  // mask -> LDS once: wave w covers floats [w*256, (w+1)*256)
  GLD16(mp + w * 256 + lane * 4, &Ms[w * 256]);

  f32x4 otA[4], otB[4];
#pragma unroll
  for (int i = 0; i < 4; ++i) {
    otA[i] = (f32x4){0.f, 0.f, 0.f, 0.f};
    otB[i] = (f32x4){0.f, 0.f, 0.f, 0.f};
  }
  float lA = 0.f, lB = 0.f;

  auto stageK = [&](int buf, int key) {
    GLD16(Kg + (size_t)key * DKH, &Ks[buf][sw * 1024]);
    GLD16(Kg + (size_t)key * DKH + 32, &Ks[buf][sw * 1024 + 512]);
    GLD16(Kg + (size_t)(key + 64) * DKH, &Ks[buf][(sw + 4) * 1024]);
    GLD16(Kg + (size_t)(key + 64) * DKH + 32, &Ks[buf][(sw + 4) * 1024 + 512]);
  };
  auto stageV = [&](int buf, int key) {
    GLD16(Vg + key, &Vs[buf][sw * 2048]);
    GLD16(Vg + key + 32, &Vs[buf][sw * 2048 + 512]);
    GLD16(Vg + key + 64, &Vs[buf][sw * 2048 + 1024]);
    GLD16(Vg + key + 96, &Vs[buf][sw * 2048 + 1536]);
  };

  // prologue: tiles 0 and 1 in flight (8 GLD16/wave + 1 mask)
  if (!isV) { stageK(0, 0); stageK(1, 128); }
  else      { stageV(0, 0); stageV(1, 128); }

  for (int kt = 0; kt < T_SEQ / 128; ++kt) {
    const int cb = kt & 3;
    const int key0 = kt * 128;
    if (kt + 2 < T_SEQ / 128) {
      if (!isV) stageK((kt + 2) & 3, key0 + 256);
      else      stageV((kt + 2) & 3, key0 + 256);
    }
    // counted wait: own tile-kt loads complete; 2 tiles stay in flight.
    if (kt + 2 < T_SEQ / 128)      asm volatile("s_waitcnt vmcnt(8)" ::: "memory");
    else if (kt + 1 < T_SEQ / 128) asm volatile("s_waitcnt vmcnt(4)" ::: "memory");
    else                           asm volatile("s_waitcnt vmcnt(0)" ::: "memory");
    __builtin_amdgcn_s_barrier();
    __builtin_amdgcn_sched_barrier(0);

    // S^T per 16-key subtile; each ka read feeds both q-fragments.
    // QK accumulator seeded with the additive mask (C-in of first MFMA).
    halfx8 pbA[4], pbB[4];
#pragma unroll
    for (int kp = 0; kp < 4; ++kp) {
      unsigned peA0, peA1, poA0, poA1;
      unsigned peB0, peB1, poB0, poB1;
#pragma unroll
      for (int hf = 0; hf < 2; ++hf) {
        const int nt = kp * 2 + hf;
        bf16x8 ka0 = *(const bf16x8*)&Ks[cb][nt * 1024 + quad * 128 + lm * 8];
        bf16x8 ka1 = *(const bf16x8*)&Ks[cb][nt * 1024 + 512 + quad * 128 + lm * 8];
        const float4 m4 = *(const float4*)&Ms[key0 + nt * 16 + quad * 4];
        const f32x4 mseed = (f32x4){m4.x, m4.y, m4.z, m4.w};
        f32x4 sA = mseed;
        sA = __builtin_amdgcn_mfma_f32_16x16x32_bf16(ka0, qbA0, sA, 0, 0, 0);
        sA = __builtin_amdgcn_mfma_f32_16x16x32_bf16(ka1, qbA1, sA, 0, 0, 0);
        f32x4 sB = mseed;
        sB = __builtin_amdgcn_mfma_f32_16x16x32_bf16(ka0, qbB0, sB, 0, 0, 0);
        sB = __builtin_amdgcn_mfma_f32_16x16x32_bf16(ka1, qbB1, sB, 0, 0, 0);
        float a0 = fexp2(sA[0]);
        float a1 = fexp2(sA[1]);
        float a2 = fexp2(sA[2]);
        float a3 = fexp2(sA[3]);
        lA += (a0 + a1) + (a2 + a3);
        float b0 = fexp2(sB[0]);
        float b1 = fexp2(sB[1]);
        float b2 = fexp2(sB[2]);
        float b3 = fexp2(sB[3]);
        lB += (b0 + b1) + (b2 + b3);
        unsigned loA = __builtin_bit_cast(unsigned, pkh(a0, a1));
        unsigned hiA = __builtin_bit_cast(unsigned, pkh(a2, a3));
        unsigned loB = __builtin_bit_cast(unsigned, pkh(b0, b1));
        unsigned hiB = __builtin_bit_cast(unsigned, pkh(b2, b3));
        if (hf == 0) {
          peA0 = loA; peA1 = hiA; peB0 = loB; peB1 = hiB;
        } else {
          poA0 = loA; poA1 = hiA; poB0 = loB; poB1 = hiB;
        }
      }
      {
        unsigned x0 = peA0, y0 = poA0, x1 = peA1, y1 = poA1;
        swap32(x0, y0); swap16(x0, y0);
        swap32(x1, y1); swap16(x1, y1);
        pbA[kp] = __builtin_bit_cast(halfx8, (uintx4){x0, x1, y0, y1});
      }
      {
        unsigned x0 = peB0, y0 = poB0, x1 = peB1, y1 = poB1;
        swap32(x0, y0); swap16(x0, y0);
        swap32(x1, y1); swap16(x1, y1);
        pbB[kp] = __builtin_bit_cast(halfx8, (uintx4){x0, x1, y0, y1});
      }
    }

    // O^T += V^T.P^T : each va read feeds both fragments' MFMAs.
#pragma unroll
    for (int nt2 = 0; nt2 < 4; ++nt2) {
#pragma unroll
      for (int kp = 0; kp < 4; ++kp) {
        halfx8 va =
            *(const halfx8*)&Vs[cb][nt2 * 2048 + kp * 512 + quad * 128 + lm * 8];
        otA[nt2] =
            __builtin_amdgcn_mfma_f32_16x16x32_f16(va, pbA[kp], otA[nt2], 0, 0, 0);
        otB[nt2] =
            __builtin_amdgcn_mfma_f32_16x16x32_f16(va, pbB[kp], otB[nt2], 0, 0, 0);
      }
    }
  }
  lA += __shfl_xor(lA, 16, 64);
  lA += __shfl_xor(lA, 32, 64);
  lB += __shfl_xor(lB, 16, 64);
  lB += __shfl_xor(lB, 32, 64);
  const float invA = 1.f / lA;
  const float invB = 1.f / lB;
  const size_t rowA = (size_t)(b * T_SEQ + q0 + lm) * DM + h * DKH;
  const size_t rowB = rowA + (size_t)16 * DM;
#pragma unroll
  for (int nt = 0; nt < 4; ++nt) {
    short2 a = pk2(otA[nt][0] * invA, otA[nt][1] * invA);
    short2 c = pk2(otA[nt][2] * invA, otA[nt][3] * invA);
    short4 o4 = {a.x, a.y, c.x, c.y};
    *(short4*)(Ao + rowA + nt * 16 + quad * 4) = o4;
    short2 e = pk2(otB[nt][0] * invB, otB[nt][1] * invB);
    short2 g = pk2(otB[nt][2] * invB, otB[nt][3] * invB);
    short4 o5 = {e.x, e.y, g.x, g.y};
    *(short4*)(Ao + rowB + nt * 16 + quad * 4) = o5;
  }
}

extern "C" void kernel_launch(void* const* d_in, const int* in_sizes, int n_in,
                              void* d_out, int out_size, void* d_ws, size_t ws_size,
                              hipStream_t stream) {
  const float* q = (const float*)d_in[0];
  const float* k = (const float*)d_in[1];
  const float* v = (const float*)d_in[2];
  const int* mk = (const int*)d_in[3];
  const float* Wq = (const float*)d_in[4];
  const float* bq = (const float*)d_in[5];
  const float* Wk = (const float*)d_in[6];
  const float* bk = (const float*)d_in[7];
  const float* Wv = (const float*)d_in[8];
  const float* bv = (const float*)d_in[9];
  const float* Wo = (const float*)d_in[10];
  const float* bo = (const float*)d_in[11];

  const size_t XE = (size_t)M_ROWS * DM;  // 4194304
  const size_t WE = (size_t)DM * DM;      // 1048576
  short* xb = (short*)d_ws;               // 3*XE (dead after QKV gemm)
  short* Wt = xb + 3 * XE;                // 4*WE
  short* Qh = Wt + 4 * WE;                // 3*XE: Qh, Kh, Vt(f16)
  float* mf = (float*)(Qh + 3 * XE);      // 4096 floats
  short* Ao = xb;                         // alias

  prep_all<<<dim3(16, 16, 7), 256, 0, stream>>>(q, k, v, mk, Wq, Wk, Wv, Wo,
                                                xb, Wt, mf);
  gemm_qkv<<<dim3(M_ROWS / 128, DM / 128, 3), 512, 0, stream>>>(
      xb, Wt, bq, bk, bv, Qh);
  attn_kernel<<<dim3(T_SEQ / 256, NB * NH), 512, 0, stream>>>(
      Qh, Qh + XE, Qh + 2 * XE, mf, Ao);
  gemm_out<<<dim3(M_ROWS / 128, DM / 128), 512, 0, stream>>>(
      Ao, Wt + 3 * WE, bo, (float*)d_out);
}